// Round 6
// baseline (123.812 us; speedup 1.0000x reference)
//
#include <hip/hip_runtime.h>

// Problem constants (from reference setup_inputs)
#define BB 4
#define CC 12
#define DD 8
#define HG 16
#define WG 16
#define HH 1024
#define WW 1024

// Native 4-float vector (clang ext vector) — legal for nontemporal builtins
// and lowers arithmetic to v_pk_fma_f32 (2 FP32 FMAs per issue).
typedef float vf4 __attribute__((ext_vector_type(4)));

// f32 slab: per row, S[x * XSTRIDE + z*CC + c] (dwords).
// XSTRIDE = 100 -> bank = (4x + 12z + k) mod 32: x residues {0,4,8,12,16},
// z residues {0,12,24,4,16,28,8,20} all distinct -> random-z conflicts ~min.
// Cell base dword = 100x + 12z, both multiples of 4 -> 16B-aligned b128 reads.
#define XSTRIDE 100
#define ROWS 2   // rows per block; fy is constant over 64-row bands starting
                 // at h=32+64m, so 2-aligned row pairs never straddle a band

__global__ __launch_bounds__(256) void slice_apply(
    const float* __restrict__ grid,   // [B,C,D,HG,WG]
    const float* __restrict__ guide,  // [B,H,W]
    const float* __restrict__ img,    // [B,3,H,W]
    float* __restrict__ out)          // [B,3,H,W]
{
    __shared__ float S[ROWS * WG * XSTRIDE];  // 2 * 6400 B = 12800 B

    const int blk = blockIdx.x;
    const int b  = blk >> 9;                 // HH/ROWS = 512 row-groups per batch
    const int h0 = (blk & 511) * ROWS;

    // y-cell pair shared by both rows of this block
    const float gy0 = (h0 + 0.5f) * ((float)HG / (float)HH);
    const float fy  = floorf(gy0 - 0.5f);
    const int   iy0 = max(0, min(HG - 1, (int)fy));
    const int   iy1 = max(0, min(HG - 1, (int)fy + 1));

    float tyr[ROWS];
    #pragma unroll
    for (int r = 0; r < ROWS; ++r) {
        const float gy = (h0 + r + 0.5f) * ((float)HG / (float)HH);
        tyr[r] = gy - 0.5f - fy;            // ty in [0,1)
    }

    // ---- Hoist the global pixel stream ABOVE the barrier so it overlaps
    // staging latency. 2 rows * (1 guide + 3 image) vf4 = 32 VGPRs held.
    const int w0 = threadIdx.x * 4;
    vf4 g4v[ROWS], i0v[ROWS], i1v[ROWS], i2v[ROWS];
    #pragma unroll
    for (int r = 0; r < ROWS; ++r) {
        const int h = h0 + r;
        const size_t pix = ((size_t)b * HH + h) * WW + w0;
        g4v[r] = *reinterpret_cast<const vf4*>(guide + pix);
        const float* ib = img + (((size_t)b * 3) * HH + h) * WW + w0;
        i0v[r] = __builtin_nontemporal_load(reinterpret_cast<const vf4*>(ib));
        i1v[r] = __builtin_nontemporal_load(reinterpret_cast<const vf4*>(ib + (size_t)HH * WW));
        i2v[r] = __builtin_nontemporal_load(reinterpret_cast<const vf4*>(ib + (size_t)2 * HH * WW));
    }

    // Stage: load the two raw y-slices once, fold into ROWS per-row slabs.
    // 1536 cells / 256 threads = 6 iters; (c,z,x) flat order, x fastest.
    for (int j = threadIdx.x; j < CC * DD * WG; j += 256) {
        const int x = j & 15;
        const int z = (j >> 4) & 7;
        const int c = j >> 7;
        const size_t base = ((size_t)(b * CC + c) * DD + z) * (HG * WG);
        const float v0 = grid[base + iy0 * WG + x];
        const float v1 = grid[base + iy1 * WG + x];
        const int so = x * XSTRIDE + z * CC + c;
        #pragma unroll
        for (int r = 0; r < ROWS; ++r)
            S[r * (WG * XSTRIDE) + so] = v0 + tyr[r] * (v1 - v0);
    }
    __syncthreads();

    // x cell pair is uniform across the 4 pixels of this thread
    const float scale = (float)WG / (float)WW;       // 1/64
    const float gx0 = (w0 + 0.5f) * scale;
    const float fx  = floorf(gx0 - 0.5f);
    const float tx0 = gx0 - 0.5f - fx;
    const int   ix0 = max(0, min(WG - 1, (int)fx));
    const int   ix1 = max(0, min(WG - 1, (int)fx + 1));

    #pragma unroll
    for (int r = 0; r < ROWS; ++r) {
        const int h = h0 + r;
        const float* Sr  = S + r * (WG * XSTRIDE);
        const float* Sx0 = Sr + ix0 * XSTRIDE;
        const float* Sx1 = Sr + ix1 * XSTRIDE;

        const vf4 g4 = g4v[r];
        const vf4 i0 = i0v[r], i1 = i1v[r], i2 = i2v[r];
        vf4 o0, o1, o2;

        #pragma unroll
        for (int p = 0; p < 4; ++p) {
            const float tx  = tx0 + (float)p * scale;
            const float wx0 = 1.0f - tx, wx1 = tx;

            const float gz  = g4[p] * (float)DD;
            const float fz  = floorf(gz - 0.5f);
            const float tz  = gz - 0.5f - fz;
            const int   iz0 = max(0, min(DD - 1, (int)fz));
            const int   iz1 = max(0, min(DD - 1, (int)fz + 1));
            const float wz0 = 1.0f - tz, wz1 = tz;

            const float w00 = wz0 * wx0, w01 = wz0 * wx1;
            const float w10 = wz1 * wx0, w11 = wz1 * wx1;

            // vf4 accumulators -> v_pk_fma_f32 (2 FMAs per issue)
            vf4 accA = 0.0f, accB = 0.0f, accC = 0.0f;

            auto accum = [&](const float* P, float w) {
                const vf4 a = *reinterpret_cast<const vf4*>(P);
                const vf4 e = *reinterpret_cast<const vf4*>(P + 4);
                const vf4 f = *reinterpret_cast<const vf4*>(P + 8);
                accA += w * a;
                accB += w * e;
                accC += w * f;
            };
            accum(Sx0 + iz0 * CC, w00);
            accum(Sx1 + iz0 * CC, w01);
            accum(Sx0 + iz1 * CC, w10);
            accum(Sx1 + iz1 * CC, w11);

            const float im0 = i0[p];
            const float im1 = i1[p];
            const float im2 = i2[p];

            o0[p] = accA[0] * im0 + accA[1] * im1 + accA[2] * im2 + accA[3];
            o1[p] = accB[0] * im0 + accB[1] * im1 + accB[2] * im2 + accB[3];
            o2[p] = accC[0] * im0 + accC[1] * im1 + accC[2] * im2 + accC[3];
        }

        float* ob = out + (((size_t)b * 3) * HH + h) * WW + w0;
        __builtin_nontemporal_store(o0, reinterpret_cast<vf4*>(ob));
        __builtin_nontemporal_store(o1, reinterpret_cast<vf4*>(ob + (size_t)HH * WW));
        __builtin_nontemporal_store(o2, reinterpret_cast<vf4*>(ob + (size_t)2 * HH * WW));
    }
}

extern "C" void kernel_launch(void* const* d_in, const int* in_sizes, int n_in,
                              void* d_out, int out_size, void* d_ws, size_t ws_size,
                              hipStream_t stream) {
    const float* grid  = (const float*)d_in[0];
    const float* guide = (const float*)d_in[1];
    const float* image = (const float*)d_in[2];
    float* out = (float*)d_out;

    const int nblocks = BB * HH / ROWS;  // 2048 blocks, 2 rows each -> 8/CU
    slice_apply<<<nblocks, 256, 0, stream>>>(grid, guide, image, out);
}